// Round 6
// baseline (229.087 us; speedup 1.0000x reference)
//
#include <hip/hip_runtime.h>
#include <math.h>

// MoE router: X[8192,4096] fp32 @ W^T -> logits[8192,64] -> top2 softmax scatter.
// d_out = probs[8192*64] ++ routing_map[8192*64] (floats).
// ws: part [HG][8192][64] fp32 (16MB @ HG=8, 32MB @ HG=16; runtime-gated)
//
// R1: lane=token raw X reads -> 4x overfetch. Fixed via LDS staging.
// R2: 96us. VALU-busy TIME == 27.3us FMA floor; duty 30% -- SMEM W row needs
//     lgkmcnt(0) full drain per j (SMEM retires OOO; prefetch unfixable).
// R3 FAILED: 2 tokens/lane -> ~170 live VGPRs -> scratch traffic. acc <= 64.
// R4 FAILED: per-j ds_read_b128 W broadcast floods the per-CU LDS pipe.
// R5: 8x8 reg-tile outer product, 1-wave blocks: 90us, duty 41%. VALU time
//     still ~= floor. Limiter: 1024 waves = 1 wave/SIMD -- zero TLP, every
//     vmcnt/LDS bubble exposed (per-chunk mem 3.1K cyc > compute 2K cyc).
// R6: HG=16 -> 2048 single-wave blocks = 2 waves/SIMD (VGPR 192 fits the
//     129-256 band). X still read once; part doubles (ws_size-gated).

#define HDIM 4096
#define NEXP 64
#define NTOK 8192
#define KK 16               // k per staged chunk
#define TPBK 64             // tokens per wave
#define XS 68               // LDS row stride (floats): 16B-aligned rows, ~2-way banks

// ---------------- kernel 1: partial logits (templated on K-split) ----------------
template<int HG>
__global__ __launch_bounds__(64) void logits_kernel(
        const float* __restrict__ X, const float* __restrict__ W,
        float* __restrict__ part) {
    constexpr int HSLAB = HDIM / HG;
    constexpr int NCH   = HSLAB / KK;

    const int tg   = blockIdx.x / HG;
    const int hg   = blockIdx.x % HG;
    const int lane = threadIdx.x;       // 0..63
    const int tr   = lane >> 3;         // token-row group 0..7
    const int ec   = lane & 7;          // expert-col group 0..7

    __shared__ __align__(16) float smem[2 * KK * XS];   // 8704 B
    float* xs = smem;                   // [KK][XS]: xs[k][token]
    float* ws = smem + KK * XS;         // [KK][XS]: ws[k][expert]

    const int token0 = tg * TPBK;
    const int hbase  = hg * HSLAB;

    const int r4 = lane >> 2;           // 0..15
    const int sl = lane & 3;            // 0..3

    float acc[8][8];
    #pragma unroll
    for (int i = 0; i < 8; ++i)
        #pragma unroll
        for (int j = 0; j < 8; ++j) acc[i][j] = 0.f;

    const float* Xb = X + (size_t)token0 * HDIM + hbase;

    float4 pfx[4], pfw[4];
    // ---- prologue: load + store chunk 0 ----
    #pragma unroll
    for (int p = 0; p < 4; ++p) {       // x tile 64t x 16k, 4 lanes/row coalesced
        int row = p * 16 + r4;
        pfx[p] = *reinterpret_cast<const float4*>(Xb + (size_t)row * HDIM + sl * 4);
    }
    #pragma unroll
    for (int q = 0; q < 4; ++q) {       // w tile 64e x 16k
        int idx = q * 64 + lane;
        int e = idx >> 2, s2 = idx & 3;
        pfw[q] = *reinterpret_cast<const float4*>(W + (size_t)e * HDIM + hbase + s2 * 4);
    }
    #pragma unroll
    for (int p = 0; p < 4; ++p) {       // transpose-scatter to k-major
        int row = p * 16 + r4;
        xs[(sl * 4 + 0) * XS + row] = pfx[p].x;
        xs[(sl * 4 + 1) * XS + row] = pfx[p].y;
        xs[(sl * 4 + 2) * XS + row] = pfx[p].z;
        xs[(sl * 4 + 3) * XS + row] = pfx[p].w;
    }
    #pragma unroll
    for (int q = 0; q < 4; ++q) {
        int idx = q * 64 + lane;
        int e = idx >> 2, s2 = idx & 3;
        ws[(s2 * 4 + 0) * XS + e] = pfw[q].x;
        ws[(s2 * 4 + 1) * XS + e] = pfw[q].y;
        ws[(s2 * 4 + 2) * XS + e] = pfw[q].z;
        ws[(s2 * 4 + 3) * XS + e] = pfw[q].w;
    }
    __syncthreads();                    // single wave: just orders LDS

    for (int c = 0; c < NCH; ++c) {
        if (c + 1 < NCH) {              // global prefetch of next chunk
            const int off = (c + 1) * KK;
            #pragma unroll
            for (int p = 0; p < 4; ++p) {
                int row = p * 16 + r4;
                pfx[p] = *reinterpret_cast<const float4*>(
                    Xb + (size_t)row * HDIM + off + sl * 4);
            }
            #pragma unroll
            for (int q = 0; q < 4; ++q) {
                int idx = q * 64 + lane;
                int e = idx >> 2, s2 = idx & 3;
                pfw[q] = *reinterpret_cast<const float4*>(
                    W + (size_t)e * HDIM + hbase + off + s2 * 4);
            }
        }
        // ---- compute: per k, 4 ds_read_b128 -> 64 FMAs ----
        #pragma unroll
        for (int k = 0; k < KK; ++k) {
            const float4* xr = reinterpret_cast<const float4*>(xs + k * XS + tr * 8);
            const float4* wr = reinterpret_cast<const float4*>(ws + k * XS + ec * 8);
            float4 xa = xr[0], xb = xr[1];
            float4 wa = wr[0], wb = wr[1];
            float xv[8] = {xa.x, xa.y, xa.z, xa.w, xb.x, xb.y, xb.z, xb.w};
            float wv[8] = {wa.x, wa.y, wa.z, wa.w, wb.x, wb.y, wb.z, wb.w};
            #pragma unroll
            for (int i = 0; i < 8; ++i)
                #pragma unroll
                for (int j = 0; j < 8; ++j)
                    acc[i][j] = fmaf(xv[i], wv[j], acc[i][j]);
        }
        __syncthreads();
        if (c + 1 < NCH) {              // commit prefetched chunk to LDS
            #pragma unroll
            for (int p = 0; p < 4; ++p) {
                int row = p * 16 + r4;
                xs[(sl * 4 + 0) * XS + row] = pfx[p].x;
                xs[(sl * 4 + 1) * XS + row] = pfx[p].y;
                xs[(sl * 4 + 2) * XS + row] = pfx[p].z;
                xs[(sl * 4 + 3) * XS + row] = pfx[p].w;
            }
            #pragma unroll
            for (int q = 0; q < 4; ++q) {
                int idx = q * 64 + lane;
                int e = idx >> 2, s2 = idx & 3;
                ws[(s2 * 4 + 0) * XS + e] = pfw[q].x;
                ws[(s2 * 4 + 1) * XS + e] = pfw[q].y;
                ws[(s2 * 4 + 2) * XS + e] = pfw[q].z;
                ws[(s2 * 4 + 3) * XS + e] = pfw[q].w;
            }
        }
        __syncthreads();
    }

    // ---- epilogue: per lane 8 tokens x 8 consecutive experts ----
    float* dst = part + ((size_t)hg * NTOK + token0) * NEXP;
    #pragma unroll
    for (int i = 0; i < 8; ++i) {
        int t = tr * 8 + i;
        *reinterpret_cast<float4*>(dst + (size_t)t * NEXP + ec * 8) =
            make_float4(acc[i][0], acc[i][1], acc[i][2], acc[i][3]);
        *reinterpret_cast<float4*>(dst + (size_t)t * NEXP + ec * 8 + 4) =
            make_float4(acc[i][4], acc[i][5], acc[i][6], acc[i][7]);
    }
}

// ---------------- kernel 2: reduce HG partials, top-2 softmax, scatter ----------------
template<int HG>
__global__ __launch_bounds__(256) void topk_kernel(
        const float* __restrict__ part, float* __restrict__ probs,
        float* __restrict__ rmap) {
    const int wave = threadIdx.x >> 6;
    const int lane = threadIdx.x & 63;       // lane = expert
    const int token = blockIdx.x * 4 + wave;

    const float* p = part + (size_t)token * NEXP + lane;
    float v = 0.f;
    #pragma unroll
    for (int hg = 0; hg < HG; ++hg) v += p[(size_t)hg * NTOK * NEXP];

    // top-1 (lower index wins ties, like lax.top_k)
    float m1 = v; int i1 = lane;
    #pragma unroll
    for (int s = 32; s > 0; s >>= 1) {
        float om = __shfl_xor(m1, s, 64);
        int   oi = __shfl_xor(i1, s, 64);
        if (om > m1 || (om == m1 && oi < i1)) { m1 = om; i1 = oi; }
    }
    // top-2: exclude i1
    float vx = (lane == i1) ? -INFINITY : v;
    float m2 = vx; int i2 = lane;
    #pragma unroll
    for (int s = 32; s > 0; s >>= 1) {
        float om = __shfl_xor(m2, s, 64);
        int   oi = __shfl_xor(i2, s, 64);
        if (om > m2 || (om == m2 && oi < i2)) { m2 = om; i2 = oi; }
    }

    float e2 = expf(m2 - m1);
    float p1 = 1.f / (1.f + e2);
    float p2 = 1.f - p1;

    float prob = (lane == i1) ? p1 : ((lane == i2) ? p2 : 0.f);
    float flag = (lane == i1 || lane == i2) ? 1.f : 0.f;
    probs[(size_t)token * NEXP + lane] = prob;
    rmap [(size_t)token * NEXP + lane] = flag;
}

extern "C" void kernel_launch(void* const* d_in, const int* in_sizes, int n_in,
                              void* d_out, int out_size, void* d_ws, size_t ws_size,
                              hipStream_t stream) {
    const float* X = (const float*)d_in[0];   // [8192,4096]
    const float* W = (const float*)d_in[1];   // [64,4096]
    float* out  = (float*)d_out;
    float* part = (float*)d_ws;

    const size_t need16 = (size_t)16 * NTOK * NEXP * sizeof(float);  // 32 MB
    if (ws_size >= need16) {
        logits_kernel<16><<<128 * 16, 64, 0, stream>>>(X, W, part);
        topk_kernel<16><<<NTOK / 4, 256, 0, stream>>>(part, out, out + (size_t)NTOK * NEXP);
    } else {
        logits_kernel<8><<<128 * 8, 64, 0, stream>>>(X, W, part);
        topk_kernel<8><<<NTOK / 4, 256, 0, stream>>>(part, out, out + (size_t)NTOK * NEXP);
    }
}